// Round 1
// baseline (216.254 us; speedup 1.0000x reference)
//
#include <hip/hip_runtime.h>

typedef unsigned short u16;
typedef __attribute__((ext_vector_type(8))) short bf16x8;
typedef __attribute__((ext_vector_type(4))) float f32x4;

#define MFMA16(a, b, c) __builtin_amdgcn_mfma_f32_16x16x32_bf16((a), (b), (c), 0, 0, 0)

__device__ __forceinline__ void async_lds16(void* lds, const void* g) {
  __builtin_amdgcn_global_load_lds(
      (const __attribute__((address_space(1))) void*)g,
      (__attribute__((address_space(3))) void*)lds, 16, 0, 0);
}

__device__ __forceinline__ u16 f2bf(float f) {
  union { float f; unsigned u; } v; v.f = f;
  unsigned r = v.u + 0x7fffu + ((v.u >> 16) & 1u);
  return (u16)(r >> 16);
}

// ---------------- preprocess kernels ----------------

__global__ __launch_bounds__(256) void k_cvt(const float* __restrict__ in, u16* __restrict__ out, int n) {
  int i = (blockIdx.x * 256 + threadIdx.x) * 4;
  if (i >= n) return;
  float4 v = *(const float4*)(in + i);
  ushort4 o;
  o.x = f2bf(v.x); o.y = f2bf(v.y); o.z = f2bf(v.z); o.w = f2bf(v.w);
  *(ushort4*)(out + i) = o;
}

// in: f32 [R][C]  ->  out: bf16 [C][R]
__global__ __launch_bounds__(256) void k_transpose_cvt(const float* __restrict__ in, u16* __restrict__ out,
                                                       int R, int C) {
  __shared__ float tile[32][33];
  int c0 = blockIdx.x * 32, r0 = blockIdx.y * 32;
  int tx = threadIdx.x & 31, ty = threadIdx.x >> 5;
#pragma unroll
  for (int i = 0; i < 32; i += 8)
    tile[ty + i][tx] = in[(long)(r0 + ty + i) * C + c0 + tx];
  __syncthreads();
#pragma unroll
  for (int i = 0; i < 32; i += 8)
    out[(long)(c0 + ty + i) * R + r0 + tx] = f2bf(tile[tx][ty + i]);
}

// V [32 bh][2048 s][64 d] -> Vt [32 bh][64 d][2048 s]   (bf16)
__global__ __launch_bounds__(256) void k_transpose_v(const u16* __restrict__ V, u16* __restrict__ Vt) {
  int bh = blockIdx.z;
  int s0 = blockIdx.x * 32, d0 = blockIdx.y * 32;
  __shared__ u16 tile[32][33];
  int tx = threadIdx.x & 31, ty = threadIdx.x >> 5;
  const u16* Vb = V + (long)bh * 2048 * 64;
  u16* Vtb = Vt + (long)bh * 64 * 2048;
#pragma unroll
  for (int i = 0; i < 32; i += 8)
    tile[ty + i][tx] = Vb[(long)(s0 + ty + i) * 64 + d0 + tx];
  __syncthreads();
#pragma unroll
  for (int i = 0; i < 32; i += 8)
    Vtb[(long)(d0 + ty + i) * 2048 + s0 + tx] = tile[tx][ty + i];
}

// ---------------- NT GEMM core: C[128x128] = A[128xK] * Bt[128xK]^T ----------------
// LDS tiles [128 rows][64 k] bf16, chunk-swizzled: element (r, k) at byte r*128 + ((k*2) ^ ((r&7)<<4))

__device__ __forceinline__ void gemm_core(const u16* __restrict__ A, const u16* __restrict__ Bt,
                                          int K, long row0, long col0,
                                          u16* sA, u16* sB, f32x4 acc[4][4]) {
  const int t = threadIdx.x;
  const int lane = t & 63, g = lane >> 4, m16 = lane & 15;
  const int wid = t >> 6, wr = wid >> 1, wc = wid & 1;
  const int ldsbase = (t & ~63) << 4;  // wave-uniform byte base within a 4KB slab
  const int nkt = K >> 6;
  for (int kt = 0; kt < nkt; ++kt) {
    const int k0 = kt << 6;
    __syncthreads();
#pragma unroll
    for (int it = 0; it < 4; ++it) {
      int i = it * 256 + t;
      int r = i >> 3, c = i & 7;
      int cs = c ^ (r & 7);  // pre-swizzled global source, linear LDS dest
      async_lds16((char*)sA + it * 4096 + ldsbase, A + (row0 + r) * K + k0 + cs * 8);
    }
#pragma unroll
    for (int it = 0; it < 4; ++it) {
      int i = it * 256 + t;
      int r = i >> 3, c = i & 7;
      int cs = c ^ (r & 7);
      async_lds16((char*)sB + it * 4096 + ldsbase, Bt + (col0 + r) * K + k0 + cs * 8);
    }
    __syncthreads();  // compiler emits vmcnt(0) drain here
#pragma unroll
    for (int kk6 = 0; kk6 < 2; ++kk6) {
      const int ke = kk6 * 32 + 8 * g;
      bf16x8 av[4], bv[4];
#pragma unroll
      for (int mi = 0; mi < 4; ++mi) {
        int row = wr * 64 + mi * 16 + m16;
        av[mi] = *(const bf16x8*)((const char*)sA + (row << 7) + ((ke << 1) ^ ((row & 7) << 4)));
      }
#pragma unroll
      for (int ni = 0; ni < 4; ++ni) {
        int row = wc * 64 + ni * 16 + m16;
        bv[ni] = *(const bf16x8*)((const char*)sB + (row << 7) + ((ke << 1) ^ ((row & 7) << 4)));
      }
#pragma unroll
      for (int mi = 0; mi < 4; ++mi)
#pragma unroll
        for (int ni = 0; ni < 4; ++ni)
          acc[mi][ni] = MFMA16(av[mi], bv[ni], acc[mi][ni]);
    }
  }
}

// GEMM1: xb[4096][1024] x wqkvT[3072][1024]^T -> scatter Q,K,V [B,H,S,D] bf16 (Q scaled by 0.125)
__global__ __launch_bounds__(256) void k_gemm_qkv(const u16* __restrict__ xb, const u16* __restrict__ wT,
                                                  u16* __restrict__ Qo, u16* __restrict__ Ko,
                                                  u16* __restrict__ Vo) {
  __shared__ __align__(16) u16 sA[128 * 64];
  __shared__ __align__(16) u16 sB[128 * 64];
  f32x4 acc[4][4];
  const f32x4 z = {0.f, 0.f, 0.f, 0.f};
#pragma unroll
  for (int mi = 0; mi < 4; ++mi)
#pragma unroll
    for (int ni = 0; ni < 4; ++ni) acc[mi][ni] = z;
  long row0 = (long)blockIdx.y * 128, col0 = (long)blockIdx.x * 128;
  gemm_core(xb, wT, 1024, row0, col0, sA, sB, acc);
  const int t = threadIdx.x;
  const int lane = t & 63, g = lane >> 4, m16 = lane & 15;
  const int wid = t >> 6, wr = wid >> 1, wc = wid & 1;
#pragma unroll
  for (int mi = 0; mi < 4; ++mi) {
#pragma unroll
    for (int ni = 0; ni < 4; ++ni) {
#pragma unroll
      for (int r = 0; r < 4; ++r) {
        int row = (int)row0 + wr * 64 + mi * 16 + 4 * g + r;
        int col = (int)col0 + wc * 64 + ni * 16 + m16;
        int h = col / 192, rem = col - h * 192;
        int which = rem >> 6, d = rem & 63;
        int b = row >> 11, s = row & 2047;
        long off = (((long)(b * 16 + h)) * 2048 + s) * 64 + d;
        float v = acc[mi][ni][r];
        if (which == 0) Qo[off] = f2bf(v * 0.125f);
        else if (which == 1) Ko[off] = f2bf(v);
        else Vo[off] = f2bf(v);
      }
    }
  }
}

// GEMM2: Ob[4096][1024] x woutT[1024][1024]^T -> out f32 [4096][1024]
__global__ __launch_bounds__(256) void k_gemm_out(const u16* __restrict__ Ob, const u16* __restrict__ wT,
                                                  float* __restrict__ out) {
  __shared__ __align__(16) u16 sA[128 * 64];
  __shared__ __align__(16) u16 sB[128 * 64];
  f32x4 acc[4][4];
  const f32x4 z = {0.f, 0.f, 0.f, 0.f};
#pragma unroll
  for (int mi = 0; mi < 4; ++mi)
#pragma unroll
    for (int ni = 0; ni < 4; ++ni) acc[mi][ni] = z;
  long row0 = (long)blockIdx.y * 128, col0 = (long)blockIdx.x * 128;
  gemm_core(Ob, wT, 1024, row0, col0, sA, sB, acc);
  const int t = threadIdx.x;
  const int lane = t & 63, g = lane >> 4, m16 = lane & 15;
  const int wid = t >> 6, wr = wid >> 1, wc = wid & 1;
#pragma unroll
  for (int mi = 0; mi < 4; ++mi) {
#pragma unroll
    for (int ni = 0; ni < 4; ++ni) {
#pragma unroll
      for (int r = 0; r < 4; ++r) {
        long row = row0 + wr * 64 + mi * 16 + 4 * g + r;
        long col = col0 + wc * 64 + ni * 16 + m16;
        out[row * 1024 + col] = acc[mi][ni][r];
      }
    }
  }
}

// ---------------- causal flash attention ----------------
// Q,K: [32 bh][2048][64] bf16 (Q pre-scaled by 0.125); Vt: [32 bh][64][2048] bf16
// O: [4096 rows = b*2048+s][1024 cols = h*64+d] bf16
__global__ __launch_bounds__(256) void k_attn(const u16* __restrict__ Qg, const u16* __restrict__ Kg,
                                              const u16* __restrict__ Vtg, u16* __restrict__ Og) {
  __shared__ __align__(16) u16 sK[64 * 64];   // [key][d] swizzled
  __shared__ __align__(16) u16 sV[64 * 64];   // [d][key] swizzled
  __shared__ __align__(16) u16 sP[4 * 16 * 64]; // per-wave [q16][key64] swizzled
  const int t = threadIdx.x;
  const int lane = t & 63, g = lane >> 4, m16 = lane & 15;
  const int wq = t >> 6;
  const int qb = blockIdx.x, bh = blockIdx.y;
  const int q0 = qb * 64;
  const u16* Qh = Qg + (long)bh * 2048 * 64;
  const u16* Kh = Kg + (long)bh * 2048 * 64;
  const u16* Vh = Vtg + (long)bh * 64 * 2048;
  const int ldsbase = (t & ~63) << 4;

  // hoisted Q fragments (16 q rows per wave)
  const int qrow = q0 + wq * 16 + m16;
  bf16x8 qf0 = *(const bf16x8*)(Qh + (long)qrow * 64 + 0 + 8 * g);
  bf16x8 qf1 = *(const bf16x8*)(Qh + (long)qrow * 64 + 32 + 8 * g);

  f32x4 acc_o[4];
  float m_run[4], l_run[4];
  const f32x4 z = {0.f, 0.f, 0.f, 0.f};
#pragma unroll
  for (int n = 0; n < 4; ++n) acc_o[n] = z;
#pragma unroll
  for (int r = 0; r < 4; ++r) { m_run[r] = -INFINITY; l_run[r] = 0.f; }

  for (int kt = 0; kt <= qb; ++kt) {
    const int kbase = kt * 64;
    __syncthreads();
#pragma unroll
    for (int it = 0; it < 2; ++it) {
      int i = it * 256 + t;
      int r = i >> 3, c = i & 7, cs = c ^ (r & 7);
      async_lds16((char*)sK + it * 4096 + ldsbase, Kh + (long)(kbase + r) * 64 + cs * 8);
    }
#pragma unroll
    for (int it = 0; it < 2; ++it) {
      int i = it * 256 + t;
      int r = i >> 3, c = i & 7, cs = c ^ (r & 7);
      async_lds16((char*)sV + it * 4096 + ldsbase, Vh + (long)r * 2048 + kbase + cs * 8);
    }
    __syncthreads();

    // S = Q K^T  (per wave: 16 q x 64 keys)
    f32x4 s_[4];
#pragma unroll
    for (int n = 0; n < 4; ++n) s_[n] = z;
#pragma unroll
    for (int kk6 = 0; kk6 < 2; ++kk6) {
      const int ke = kk6 * 32 + 8 * g;
#pragma unroll
      for (int n = 0; n < 4; ++n) {
        int row = n * 16 + m16;  // key within tile
        bf16x8 kf = *(const bf16x8*)((const char*)sK + (row << 7) + ((ke << 1) ^ ((row & 7) << 4)));
        s_[n] = MFMA16(kk6 ? qf1 : qf0, kf, s_[n]);
      }
    }

    // causal mask (only the diagonal tile needs it) + online softmax
    float p[4][4];
#pragma unroll
    for (int r = 0; r < 4; ++r) {
      const int qg_ = q0 + wq * 16 + 4 * g + r;
      if (kt == qb) {
#pragma unroll
        for (int n = 0; n < 4; ++n) {
          int key = kbase + n * 16 + m16;
          if (key > qg_) s_[n][r] = -INFINITY;
        }
      }
      float mx = fmaxf(fmaxf(s_[0][r], s_[1][r]), fmaxf(s_[2][r], s_[3][r]));
#pragma unroll
      for (int off = 1; off < 16; off <<= 1) mx = fmaxf(mx, __shfl_xor(mx, off));
      float mnew = fmaxf(m_run[r], mx);
      float sc = __expf(m_run[r] - mnew);
      m_run[r] = mnew;
      float rs = 0.f;
#pragma unroll
      for (int n = 0; n < 4; ++n) { p[n][r] = __expf(s_[n][r] - mnew); rs += p[n][r]; }
#pragma unroll
      for (int off = 1; off < 16; off <<= 1) rs += __shfl_xor(rs, off);
      l_run[r] = l_run[r] * sc + rs;
#pragma unroll
      for (int n2 = 0; n2 < 4; ++n2) acc_o[n2][r] *= sc;
    }

    // P -> LDS (wave-private, swizzled [q][key])
#pragma unroll
    for (int n = 0; n < 4; ++n)
#pragma unroll
      for (int r = 0; r < 4; ++r) {
        int row = 4 * g + r;
        int byteoff = (wq << 11) + (row << 7) + ((((n * 16 + m16) << 1)) ^ ((row & 7) << 4));
        *(u16*)((char*)sP + byteoff) = f2bf(p[n][r]);
      }

    // O += P V
#pragma unroll
    for (int kk6 = 0; kk6 < 2; ++kk6) {
      const int ke = kk6 * 32 + 8 * g;
      bf16x8 pa = *(const bf16x8*)((const char*)sP + (wq << 11) + (m16 << 7) + ((ke << 1) ^ ((m16 & 7) << 4)));
#pragma unroll
      for (int n2 = 0; n2 < 4; ++n2) {
        int vrow = n2 * 16 + m16;  // d
        bf16x8 vf = *(const bf16x8*)((const char*)sV + (vrow << 7) + ((ke << 1) ^ ((vrow & 7) << 4)));
        acc_o[n2] = MFMA16(pa, vf, acc_o[n2]);
      }
    }
  }

  // epilogue: O[row = b*2048+q][col = h*64+d]
  const int b = bh >> 4, h = bh & 15;
#pragma unroll
  for (int n2 = 0; n2 < 4; ++n2)
#pragma unroll
    for (int r = 0; r < 4; ++r) {
      int q = q0 + wq * 16 + 4 * g + r;
      long orow = (long)b * 2048 + q;
      int col = h * 64 + n2 * 16 + m16;
      Og[orow * 1024 + col] = f2bf(acc_o[n2][r] / l_run[r]);
    }
}

// ---------------- launch ----------------

extern "C" void kernel_launch(void* const* d_in, const int* in_sizes, int n_in,
                              void* d_out, int out_size, void* d_ws, size_t ws_size,
                              hipStream_t stream) {
  const float* x = (const float*)d_in[0];
  const float* w_qkv = (const float*)d_in[1];
  const float* w_out = (const float*)d_in[2];
  float* out = (float*)d_out;
  char* ws = (char*)d_ws;

  u16* xb    = (u16*)(ws + 0);          // 8 MB, reused as Ob after attention
  u16* wqkvT = (u16*)(ws + 8388608L);   // 6 MB
  u16* woutT = (u16*)(ws + 14680064L);  // 2 MB
  u16* Qb    = (u16*)(ws + 16777216L);  // 8 MB
  u16* Kb    = (u16*)(ws + 25165824L);  // 8 MB
  u16* Vb    = (u16*)(ws + 33554432L);  // 8 MB
  u16* Vt    = (u16*)(ws + 41943040L);  // 8 MB  (total 48 MB)
  u16* Ob    = xb;                      // alias: xb dead after GEMM1

  k_cvt<<<4096, 256, 0, stream>>>(x, xb, 4194304);
  k_transpose_cvt<<<dim3(96, 32), 256, 0, stream>>>(w_qkv, wqkvT, 1024, 3072);
  k_transpose_cvt<<<dim3(32, 32), 256, 0, stream>>>(w_out, woutT, 1024, 1024);
  k_gemm_qkv<<<dim3(24, 32), 256, 0, stream>>>(xb, wqkvT, Qb, Kb, Vb);
  k_transpose_v<<<dim3(64, 2, 32), 256, 0, stream>>>(Vb, Vt);
  k_attn<<<dim3(32, 32), 256, 0, stream>>>(Qb, Kb, Vt, Ob);
  k_gemm_out<<<dim3(8, 32), 256, 0, stream>>>(Ob, woutT, out);
}

// Round 2
// 155.989 us; speedup vs baseline: 1.3863x; 1.3863x over previous
//
#include <hip/hip_runtime.h>

typedef unsigned short u16;
typedef unsigned int u32;
typedef __attribute__((ext_vector_type(8))) short bf16x8;
typedef __attribute__((ext_vector_type(4))) float f32x4;

#define MFMA16(a, b, c) __builtin_amdgcn_mfma_f32_16x16x32_bf16((a), (b), (c), 0, 0, 0)

__device__ __forceinline__ void async_lds16(void* lds, const void* g) {
  __builtin_amdgcn_global_load_lds(
      (const __attribute__((address_space(1))) void*)g,
      (__attribute__((address_space(3))) void*)lds, 16, 0, 0);
}

__device__ __forceinline__ u16 f2bf(float f) {
  union { float f; unsigned u; } v; v.f = f;
  unsigned r = v.u + 0x7fffu + ((v.u >> 16) & 1u);
  return (u16)(r >> 16);
}

// ---------------- preprocess kernels ----------------

__global__ __launch_bounds__(256) void k_cvt(const float* __restrict__ in, u16* __restrict__ out, int n) {
  int i = (blockIdx.x * 256 + threadIdx.x) * 4;
  if (i >= n) return;
  float4 v = *(const float4*)(in + i);
  ushort4 o;
  o.x = f2bf(v.x); o.y = f2bf(v.y); o.z = f2bf(v.z); o.w = f2bf(v.w);
  *(ushort4*)(out + i) = o;
}

// in: f32 [R][C]  ->  out: bf16 [C][R]
__global__ __launch_bounds__(256) void k_transpose_cvt(const float* __restrict__ in, u16* __restrict__ out,
                                                       int R, int C) {
  __shared__ float tile[32][33];
  int c0 = blockIdx.x * 32, r0 = blockIdx.y * 32;
  int tx = threadIdx.x & 31, ty = threadIdx.x >> 5;
#pragma unroll
  for (int i = 0; i < 32; i += 8)
    tile[ty + i][tx] = in[(long)(r0 + ty + i) * C + c0 + tx];
  __syncthreads();
#pragma unroll
  for (int i = 0; i < 32; i += 8)
    out[(long)(c0 + ty + i) * R + r0 + tx] = f2bf(tile[tx][ty + i]);
}

// V [32 bh][2048 s][64 d] -> Vt [32 bh][64 d][2048 s]   (bf16)
__global__ __launch_bounds__(256) void k_transpose_v(const u16* __restrict__ V, u16* __restrict__ Vt) {
  int bh = blockIdx.z;
  int s0 = blockIdx.x * 32, d0 = blockIdx.y * 32;
  __shared__ u16 tile[32][33];
  int tx = threadIdx.x & 31, ty = threadIdx.x >> 5;
  const u16* Vb = V + (long)bh * 2048 * 64;
  u16* Vtb = Vt + (long)bh * 64 * 2048;
#pragma unroll
  for (int i = 0; i < 32; i += 8)
    tile[ty + i][tx] = Vb[(long)(s0 + ty + i) * 64 + d0 + tx];
  __syncthreads();
#pragma unroll
  for (int i = 0; i < 32; i += 8)
    Vtb[(long)(d0 + ty + i) * 2048 + s0 + tx] = tile[tx][ty + i];
}

// ---------------- NT GEMM core: C[128x128] = A[128xK] * Bt[128xK]^T ----------------

__device__ __forceinline__ void gemm_core(const u16* __restrict__ A, const u16* __restrict__ Bt,
                                          int K, long row0, long col0,
                                          u16* sA, u16* sB, f32x4 acc[4][4]) {
  const int t = threadIdx.x;
  const int lane = t & 63, g = lane >> 4, m16 = lane & 15;
  const int wid = t >> 6, wr = wid >> 1, wc = wid & 1;
  const int ldsbase = (t & ~63) << 4;
  const int nkt = K >> 6;
  for (int kt = 0; kt < nkt; ++kt) {
    const int k0 = kt << 6;
    __syncthreads();
#pragma unroll
    for (int it = 0; it < 4; ++it) {
      int i = it * 256 + t;
      int r = i >> 3, c = i & 7;
      int cs = c ^ (r & 7);
      async_lds16((char*)sA + it * 4096 + ldsbase, A + (row0 + r) * K + k0 + cs * 8);
    }
#pragma unroll
    for (int it = 0; it < 4; ++it) {
      int i = it * 256 + t;
      int r = i >> 3, c = i & 7;
      int cs = c ^ (r & 7);
      async_lds16((char*)sB + it * 4096 + ldsbase, Bt + (col0 + r) * K + k0 + cs * 8);
    }
    __syncthreads();
#pragma unroll
    for (int kk6 = 0; kk6 < 2; ++kk6) {
      const int ke = kk6 * 32 + 8 * g;
      bf16x8 av[4], bv[4];
#pragma unroll
      for (int mi = 0; mi < 4; ++mi) {
        int row = wr * 64 + mi * 16 + m16;
        av[mi] = *(const bf16x8*)((const char*)sA + (row << 7) + ((ke << 1) ^ ((row & 7) << 4)));
      }
#pragma unroll
      for (int ni = 0; ni < 4; ++ni) {
        int row = wc * 64 + ni * 16 + m16;
        bv[ni] = *(const bf16x8*)((const char*)sB + (row << 7) + ((ke << 1) ^ ((row & 7) << 4)));
      }
#pragma unroll
      for (int mi = 0; mi < 4; ++mi)
#pragma unroll
        for (int ni = 0; ni < 4; ++ni)
          acc[mi][ni] = MFMA16(av[mi], bv[ni], acc[mi][ni]);
    }
  }
}

// GEMM1: xb[4096][1024] x wqkvT[3072][1024]^T -> scatter Q,K,V [B,H,S,D] bf16
// Q scaled by 1/sqrt(64) * log2(e) so attention can use exp2 directly.
__global__ __launch_bounds__(256) void k_gemm_qkv(const u16* __restrict__ xb, const u16* __restrict__ wT,
                                                  u16* __restrict__ Qo, u16* __restrict__ Ko,
                                                  u16* __restrict__ Vo) {
  __shared__ __align__(16) u16 sA[128 * 64];
  __shared__ __align__(16) u16 sB[128 * 64];
  f32x4 acc[4][4];
  const f32x4 z = {0.f, 0.f, 0.f, 0.f};
#pragma unroll
  for (int mi = 0; mi < 4; ++mi)
#pragma unroll
    for (int ni = 0; ni < 4; ++ni) acc[mi][ni] = z;
  long row0 = (long)blockIdx.y * 128, col0 = (long)blockIdx.x * 128;
  gemm_core(xb, wT, 1024, row0, col0, sA, sB, acc);
  const int t = threadIdx.x;
  const int lane = t & 63, g = lane >> 4, m16 = lane & 15;
  const int wid = t >> 6, wr = wid >> 1, wc = wid & 1;
#pragma unroll
  for (int mi = 0; mi < 4; ++mi) {
#pragma unroll
    for (int ni = 0; ni < 4; ++ni) {
#pragma unroll
      for (int r = 0; r < 4; ++r) {
        int row = (int)row0 + wr * 64 + mi * 16 + 4 * g + r;
        int col = (int)col0 + wc * 64 + ni * 16 + m16;
        int h = col / 192, rem = col - h * 192;
        int which = rem >> 6, d = rem & 63;
        int b = row >> 11, s = row & 2047;
        long off = (((long)(b * 16 + h)) * 2048 + s) * 64 + d;
        float v = acc[mi][ni][r];
        if (which == 0) Qo[off] = f2bf(v * 0.18033688f);  // 0.125 * log2(e)
        else if (which == 1) Ko[off] = f2bf(v);
        else Vo[off] = f2bf(v);
      }
    }
  }
}

// GEMM2: Ob[4096][1024] x woutT[1024][1024]^T -> out f32 [4096][1024]
__global__ __launch_bounds__(256) void k_gemm_out(const u16* __restrict__ Ob, const u16* __restrict__ wT,
                                                  float* __restrict__ out) {
  __shared__ __align__(16) u16 sA[128 * 64];
  __shared__ __align__(16) u16 sB[128 * 64];
  f32x4 acc[4][4];
  const f32x4 z = {0.f, 0.f, 0.f, 0.f};
#pragma unroll
  for (int mi = 0; mi < 4; ++mi)
#pragma unroll
    for (int ni = 0; ni < 4; ++ni) acc[mi][ni] = z;
  long row0 = (long)blockIdx.y * 128, col0 = (long)blockIdx.x * 128;
  gemm_core(Ob, wT, 1024, row0, col0, sA, sB, acc);
  const int t = threadIdx.x;
  const int lane = t & 63, g = lane >> 4, m16 = lane & 15;
  const int wid = t >> 6, wr = wid >> 1, wc = wid & 1;
#pragma unroll
  for (int mi = 0; mi < 4; ++mi) {
#pragma unroll
    for (int ni = 0; ni < 4; ++ni) {
#pragma unroll
      for (int r = 0; r < 4; ++r) {
        long row = row0 + wr * 64 + mi * 16 + 4 * g + r;
        long col = col0 + wc * 64 + ni * 16 + m16;
        out[row * 1024 + col] = acc[mi][ni][r];
      }
    }
  }
}

// ---------------- causal flash attention (swapped-QK, 2 waves x 32q, KVB=128) ----------------
// Q,K: [32 bh][2048][64] bf16 (Q pre-scaled by 0.125*log2e); Vt: [32 bh][64][2048] bf16
// O rows = b*2048+s, cols = h*64+d (bf16)
__global__ __launch_bounds__(128) void k_attn(const u16* __restrict__ Qg, const u16* __restrict__ Kg,
                                              const u16* __restrict__ Vtg, u16* __restrict__ Og) {
  __shared__ __align__(16) u16 sK[2][128 * 64];   // [key][d] swizzled, double-buffered
  __shared__ __align__(16) u16 sV[2][64 * 128];   // [d][key] swizzled, double-buffered
  __shared__ __align__(16) u16 sP[2][32 * 128];   // per-wave [q][key] swizzled
  const int t = threadIdx.x;
  const int lane = t & 63, g = lane >> 4, m16 = lane & 15, w = t >> 6;
  const int L = blockIdx.x;
  // XCD-grouped + paired decode: xcd gets 4 heads; pair (pb, 31-pb) => 17 tiles/block uniform
  const int xcd = L & 7, j = L >> 3, hx = j & 3, pb = j >> 2;
  const int bh = xcd * 4 + hx;
  const int b = bh >> 4, h = bh & 15;
  const u16* Qh = Qg + (long)bh * 2048 * 64;
  const u16* Kh = Kg + (long)bh * 2048 * 64;
  const u16* Vh = Vtg + (long)bh * 64 * 2048;

  char* sKb = (char*)sK;
  char* sVb = (char*)sV;
  char* sPw = (char*)sP + w * 8192;
  const f32x4 z = {0.f, 0.f, 0.f, 0.f};

  const int qtA = pb, qtB = 31 - pb;
  const int nktA = ((qtA + 1) * 64 + 127) >> 7;
  const int nktB = ((qtB + 1) * 64 + 127) >> 7;

  auto stage = [&](int buf, int kbase) {
#pragma unroll
    for (int ps = 0; ps < 8; ++ps) {
      int i = ps * 128 + t;
      int r = i >> 3, c = i & 7, cs = c ^ (r & 7);
      async_lds16(sKb + buf * 16384 + i * 16, Kh + (long)(kbase + r) * 64 + cs * 8);
    }
#pragma unroll
    for (int ps = 0; ps < 8; ++ps) {
      int i = ps * 128 + t;
      int d = i >> 4, c = i & 15, cs = c ^ (d & 7);
      async_lds16(sVb + buf * 16384 + i * 16, Vh + (long)d * 2048 + kbase + cs * 8);
    }
  };

  int cur = 0;
  stage(0, 0);  // first tile of q-tile A

  for (int half = 0; half < 2; ++half) {
    const int qt = half ? qtB : qtA;
    const int nkt = half ? nktB : nktA;
    const int q0w = qt * 64 + w * 32;

    // hoist Q fragments (B-operand: col=q via m16, k=d contiguous)
    bf16x8 qf[2][2];
#pragma unroll
    for (int mi = 0; mi < 2; ++mi)
#pragma unroll
      for (int k6 = 0; k6 < 2; ++k6)
        qf[mi][k6] = *(const bf16x8*)(Qh + (long)(q0w + mi * 16 + m16) * 64 + k6 * 32 + 8 * g);

    f32x4 acc[2][4];
#pragma unroll
    for (int mi = 0; mi < 2; ++mi)
#pragma unroll
      for (int n2 = 0; n2 < 4; ++n2) acc[mi][n2] = z;
    float m_run[2] = {-3.0e38f, -3.0e38f};
    float l_run[2] = {0.f, 0.f};

    for (int kt = 0; kt < nkt; ++kt) {
      const int kbase = kt << 7;
      __syncthreads();  // drains previously-issued stage; tile `cur` is ready
      if (kt + 1 < nkt) stage(cur ^ 1, (kt + 1) << 7);
      else if (!half) stage(cur ^ 1, 0);  // prefetch q-tile B's first tile

      // ---- S^T = K * Q^T  (D: col=q=m16, row=key=n*16+4g+r)
      f32x4 s_[2][8];
#pragma unroll
      for (int mi = 0; mi < 2; ++mi)
#pragma unroll
        for (int n = 0; n < 8; ++n) s_[mi][n] = z;
#pragma unroll
      for (int k6 = 0; k6 < 2; ++k6) {
#pragma unroll
        for (int n = 0; n < 8; ++n) {
          int row = n * 16 + m16;
          bf16x8 kf = *(const bf16x8*)(sKb + cur * 16384 + (row << 7) +
                                       ((k6 * 64 + 16 * g) ^ ((row & 7) << 4)));
          s_[0][n] = MFMA16(kf, qf[0][k6], s_[0][n]);
          s_[1][n] = MFMA16(kf, qf[1][k6], s_[1][n]);
        }
      }

      const bool need_mask = (kbase + 127 > q0w);
#pragma unroll
      for (int mi = 0; mi < 2; ++mi) {
        const int qa = q0w + mi * 16 + m16;
        if (need_mask) {
#pragma unroll
          for (int n = 0; n < 8; ++n)
#pragma unroll
            for (int r = 0; r < 4; ++r)
              if (kbase + n * 16 + 4 * g + r > qa) s_[mi][n][r] = -3.0e38f;
        }
        float mx = s_[mi][0][0];
#pragma unroll
        for (int n = 0; n < 8; ++n)
#pragma unroll
          for (int r = 0; r < 4; ++r) mx = fmaxf(mx, s_[mi][n][r]);
        mx = fmaxf(mx, __shfl_xor(mx, 16));
        mx = fmaxf(mx, __shfl_xor(mx, 32));
        if (!__all(mx <= m_run[mi] + 8.0f)) {  // defer-max: skip rescale on small growth
          float mnew = fmaxf(m_run[mi], mx);
          float sc = exp2f(m_run[mi] - mnew);
          m_run[mi] = mnew;
          l_run[mi] *= sc;
#pragma unroll
          for (int r = 0; r < 4; ++r) {
            float scr = __shfl(sc, 4 * g + r);
#pragma unroll
            for (int n2 = 0; n2 < 4; ++n2) acc[mi][n2][r] *= scr;
          }
        }
        float rs = 0.f;
        u32 pk[8][2];
#pragma unroll
        for (int n = 0; n < 8; ++n) {
          float p0 = exp2f(s_[mi][n][0] - m_run[mi]);
          float p1 = exp2f(s_[mi][n][1] - m_run[mi]);
          float p2 = exp2f(s_[mi][n][2] - m_run[mi]);
          float p3 = exp2f(s_[mi][n][3] - m_run[mi]);
          rs += (p0 + p1) + (p2 + p3);
          pk[n][0] = (u32)f2bf(p0) | ((u32)f2bf(p1) << 16);
          pk[n][1] = (u32)f2bf(p2) | ((u32)f2bf(p3) << 16);
        }
        rs += __shfl_xor(rs, 16);
        rs += __shfl_xor(rs, 32);
        l_run[mi] += rs;
        const int qrow = mi * 16 + m16;
#pragma unroll
        for (int n = 0; n < 8; ++n) {
          int boff = (qrow << 8) + ((32 * n + 8 * g) ^ ((m16 & 7) << 4));
          *(uint2*)(sPw + boff) = make_uint2(pk[n][0], pk[n][1]);
        }
      }

      // ---- O += P V   (A=P row=q=m16; B=V col=d=m16; contraction over 128 keys)
#pragma unroll
      for (int kk = 0; kk < 4; ++kk) {
        int koff = (kk * 64 + 16 * g);
        bf16x8 pa0 = *(const bf16x8*)(sPw + (m16 << 8) + (koff ^ ((m16 & 7) << 4)));
        bf16x8 pa1 = *(const bf16x8*)(sPw + ((16 + m16) << 8) + (koff ^ ((m16 & 7) << 4)));
#pragma unroll
        for (int n2 = 0; n2 < 4; ++n2) {
          int vrow = n2 * 16 + m16;
          bf16x8 vf = *(const bf16x8*)(sVb + cur * 16384 + (vrow << 8) +
                                       (koff ^ ((vrow & 7) << 4)));
          acc[0][n2] = MFMA16(pa0, vf, acc[0][n2]);
          acc[1][n2] = MFMA16(pa1, vf, acc[1][n2]);
        }
      }
      cur ^= 1;
    }

    // epilogue for this q-tile
#pragma unroll
    for (int mi = 0; mi < 2; ++mi) {
#pragma unroll
      for (int r = 0; r < 4; ++r) {
        float lf = __shfl(l_run[mi], 4 * g + r);
        float inv = 1.0f / lf;
        int q = q0w + mi * 16 + 4 * g + r;
        long orow = (long)b * 2048 + q;
#pragma unroll
        for (int n2 = 0; n2 < 4; ++n2) {
          int col = h * 64 + n2 * 16 + m16;
          Og[orow * 1024 + col] = f2bf(acc[mi][n2][r] * inv);
        }
      }
    }
  }
}

// ---------------- launch ----------------

extern "C" void kernel_launch(void* const* d_in, const int* in_sizes, int n_in,
                              void* d_out, int out_size, void* d_ws, size_t ws_size,
                              hipStream_t stream) {
  const float* x = (const float*)d_in[0];
  const float* w_qkv = (const float*)d_in[1];
  const float* w_out = (const float*)d_in[2];
  float* out = (float*)d_out;
  char* ws = (char*)d_ws;

  u16* xb    = (u16*)(ws + 0);          // 8 MB, reused as Ob after attention
  u16* wqkvT = (u16*)(ws + 8388608L);   // 6 MB
  u16* woutT = (u16*)(ws + 14680064L);  // 2 MB
  u16* Qb    = (u16*)(ws + 16777216L);  // 8 MB
  u16* Kb    = (u16*)(ws + 25165824L);  // 8 MB
  u16* Vb    = (u16*)(ws + 33554432L);  // 8 MB
  u16* Vt    = (u16*)(ws + 41943040L);  // 8 MB  (total 48 MB)
  u16* Ob    = xb;                      // alias: xb dead after GEMM1

  k_cvt<<<4096, 256, 0, stream>>>(x, xb, 4194304);
  k_transpose_cvt<<<dim3(96, 32), 256, 0, stream>>>(w_qkv, wqkvT, 1024, 3072);
  k_transpose_cvt<<<dim3(32, 32), 256, 0, stream>>>(w_out, woutT, 1024, 1024);
  k_gemm_qkv<<<dim3(24, 32), 256, 0, stream>>>(xb, wqkvT, Qb, Kb, Vb);
  k_transpose_v<<<dim3(64, 2, 32), 256, 0, stream>>>(Vb, Vt);
  k_attn<<<dim3(512), 128, 0, stream>>>(Qb, Kb, Vt, Ob);
  k_gemm_out<<<dim3(8, 32), 256, 0, stream>>>(Ob, woutT, out);
}

// Round 3
// 153.407 us; speedup vs baseline: 1.4097x; 1.0168x over previous
//
#include <hip/hip_runtime.h>

typedef unsigned short u16;
typedef unsigned int u32;
typedef __attribute__((ext_vector_type(8))) short bf16x8;
typedef __attribute__((ext_vector_type(4))) float f32x4;

#define MFMA16(a, b, c) __builtin_amdgcn_mfma_f32_16x16x32_bf16((a), (b), (c), 0, 0, 0)

__device__ __forceinline__ void async_lds16(void* lds, const void* g) {
  __builtin_amdgcn_global_load_lds(
      (const __attribute__((address_space(1))) void*)g,
      (__attribute__((address_space(3))) void*)lds, 16, 0, 0);
}

__device__ __forceinline__ u16 f2bf(float f) {
  union { float f; unsigned u; } v; v.f = f;
  unsigned r = v.u + 0x7fffu + ((v.u >> 16) & 1u);
  return (u16)(r >> 16);
}

__device__ __forceinline__ u32 cvt_pk_bf16(float lo, float hi) {
  u32 r;
  asm("v_cvt_pk_bf16_f32 %0, %1, %2" : "=v"(r) : "v"(lo), "v"(hi));
  return r;
}

// ---------------- preprocess kernels ----------------

__global__ __launch_bounds__(256) void k_cvt(const float* __restrict__ in, u16* __restrict__ out, int n) {
  int i = (blockIdx.x * 256 + threadIdx.x) * 4;
  if (i >= n) return;
  float4 v = *(const float4*)(in + i);
  ushort4 o;
  o.x = f2bf(v.x); o.y = f2bf(v.y); o.z = f2bf(v.z); o.w = f2bf(v.w);
  *(ushort4*)(out + i) = o;
}

// in: f32 [R][C]  ->  out: bf16 [C][R]
__global__ __launch_bounds__(256) void k_transpose_cvt(const float* __restrict__ in, u16* __restrict__ out,
                                                       int R, int C) {
  __shared__ float tile[32][33];
  int c0 = blockIdx.x * 32, r0 = blockIdx.y * 32;
  int tx = threadIdx.x & 31, ty = threadIdx.x >> 5;
#pragma unroll
  for (int i = 0; i < 32; i += 8)
    tile[ty + i][tx] = in[(long)(r0 + ty + i) * C + c0 + tx];
  __syncthreads();
#pragma unroll
  for (int i = 0; i < 32; i += 8)
    out[(long)(c0 + ty + i) * R + r0 + tx] = f2bf(tile[tx][ty + i]);
}

// V [32 bh][2048 s][64 d] -> Vt [32 bh][64 d][2048 s]   (bf16)
__global__ __launch_bounds__(256) void k_transpose_v(const u16* __restrict__ V, u16* __restrict__ Vt) {
  int bh = blockIdx.z;
  int s0 = blockIdx.x * 32, d0 = blockIdx.y * 32;
  __shared__ u16 tile[32][33];
  int tx = threadIdx.x & 31, ty = threadIdx.x >> 5;
  const u16* Vb = V + (long)bh * 2048 * 64;
  u16* Vtb = Vt + (long)bh * 64 * 2048;
#pragma unroll
  for (int i = 0; i < 32; i += 8)
    tile[ty + i][tx] = Vb[(long)(s0 + ty + i) * 64 + d0 + tx];
  __syncthreads();
#pragma unroll
  for (int i = 0; i < 32; i += 8)
    Vtb[(long)(d0 + ty + i) * 2048 + s0 + tx] = tile[tx][ty + i];
}

// ---------------- NT GEMM core: C[128x128] = A[128xK] * Bt[128xK]^T ----------------

__device__ __forceinline__ void gemm_core(const u16* __restrict__ A, const u16* __restrict__ Bt,
                                          int K, long row0, long col0,
                                          u16* sA, u16* sB, f32x4 acc[4][4]) {
  const int t = threadIdx.x;
  const int lane = t & 63, g = lane >> 4, m16 = lane & 15;
  const int wid = t >> 6, wr = wid >> 1, wc = wid & 1;
  const int ldsbase = (t & ~63) << 4;
  const int nkt = K >> 6;
  for (int kt = 0; kt < nkt; ++kt) {
    const int k0 = kt << 6;
    __syncthreads();
#pragma unroll
    for (int it = 0; it < 4; ++it) {
      int i = it * 256 + t;
      int r = i >> 3, c = i & 7;
      int cs = c ^ (r & 7);
      async_lds16((char*)sA + it * 4096 + ldsbase, A + (row0 + r) * K + k0 + cs * 8);
    }
#pragma unroll
    for (int it = 0; it < 4; ++it) {
      int i = it * 256 + t;
      int r = i >> 3, c = i & 7;
      int cs = c ^ (r & 7);
      async_lds16((char*)sB + it * 4096 + ldsbase, Bt + (col0 + r) * K + k0 + cs * 8);
    }
    __syncthreads();
#pragma unroll
    for (int kk6 = 0; kk6 < 2; ++kk6) {
      const int ke = kk6 * 32 + 8 * g;
      bf16x8 av[4], bv[4];
#pragma unroll
      for (int mi = 0; mi < 4; ++mi) {
        int row = wr * 64 + mi * 16 + m16;
        av[mi] = *(const bf16x8*)((const char*)sA + (row << 7) + ((ke << 1) ^ ((row & 7) << 4)));
      }
#pragma unroll
      for (int ni = 0; ni < 4; ++ni) {
        int row = wc * 64 + ni * 16 + m16;
        bv[ni] = *(const bf16x8*)((const char*)sB + (row << 7) + ((ke << 1) ^ ((row & 7) << 4)));
      }
#pragma unroll
      for (int mi = 0; mi < 4; ++mi)
#pragma unroll
        for (int ni = 0; ni < 4; ++ni)
          acc[mi][ni] = MFMA16(av[mi], bv[ni], acc[mi][ni]);
    }
  }
}

// GEMM1: xb[4096][1024] x wqkvT[3072][1024]^T -> scatter Q,K,V [B,H,S,D] bf16
// Q scaled by 1/sqrt(64) * log2(e) so attention can use exp2 directly.
__global__ __launch_bounds__(256) void k_gemm_qkv(const u16* __restrict__ xb, const u16* __restrict__ wT,
                                                  u16* __restrict__ Qo, u16* __restrict__ Ko,
                                                  u16* __restrict__ Vo) {
  __shared__ __align__(16) u16 sA[128 * 64];
  __shared__ __align__(16) u16 sB[128 * 64];
  f32x4 acc[4][4];
  const f32x4 z = {0.f, 0.f, 0.f, 0.f};
#pragma unroll
  for (int mi = 0; mi < 4; ++mi)
#pragma unroll
    for (int ni = 0; ni < 4; ++ni) acc[mi][ni] = z;
  long row0 = (long)blockIdx.y * 128, col0 = (long)blockIdx.x * 128;
  gemm_core(xb, wT, 1024, row0, col0, sA, sB, acc);
  const int t = threadIdx.x;
  const int lane = t & 63, g = lane >> 4, m16 = lane & 15;
  const int wid = t >> 6, wr = wid >> 1, wc = wid & 1;
#pragma unroll
  for (int mi = 0; mi < 4; ++mi) {
#pragma unroll
    for (int ni = 0; ni < 4; ++ni) {
#pragma unroll
      for (int r = 0; r < 4; ++r) {
        int row = (int)row0 + wr * 64 + mi * 16 + 4 * g + r;
        int col = (int)col0 + wc * 64 + ni * 16 + m16;
        int h = col / 192, rem = col - h * 192;
        int which = rem >> 6, d = rem & 63;
        int b = row >> 11, s = row & 2047;
        long off = (((long)(b * 16 + h)) * 2048 + s) * 64 + d;
        float v = acc[mi][ni][r];
        if (which == 0) Qo[off] = f2bf(v * 0.18033688f);  // 0.125 * log2(e)
        else if (which == 1) Ko[off] = f2bf(v);
        else Vo[off] = f2bf(v);
      }
    }
  }
}

// GEMM2: Ob[4096][1024] x woutT[1024][1024]^T -> out f32 [4096][1024]
__global__ __launch_bounds__(256) void k_gemm_out(const u16* __restrict__ Ob, const u16* __restrict__ wT,
                                                  float* __restrict__ out) {
  __shared__ __align__(16) u16 sA[128 * 64];
  __shared__ __align__(16) u16 sB[128 * 64];
  f32x4 acc[4][4];
  const f32x4 z = {0.f, 0.f, 0.f, 0.f};
#pragma unroll
  for (int mi = 0; mi < 4; ++mi)
#pragma unroll
    for (int ni = 0; ni < 4; ++ni) acc[mi][ni] = z;
  long row0 = (long)blockIdx.y * 128, col0 = (long)blockIdx.x * 128;
  gemm_core(Ob, wT, 1024, row0, col0, sA, sB, acc);
  const int t = threadIdx.x;
  const int lane = t & 63, g = lane >> 4, m16 = lane & 15;
  const int wid = t >> 6, wr = wid >> 1, wc = wid & 1;
#pragma unroll
  for (int mi = 0; mi < 4; ++mi) {
#pragma unroll
    for (int ni = 0; ni < 4; ++ni) {
#pragma unroll
      for (int r = 0; r < 4; ++r) {
        long row = row0 + wr * 64 + mi * 16 + 4 * g + r;
        long col = col0 + wc * 64 + ni * 16 + m16;
        out[row * 1024 + col] = acc[mi][ni][r];
      }
    }
  }
}

// ---------------- causal flash attention ----------------
// 4 waves x 32 q (QBLK=128), KVBLK=64, double-buffered K/V. Swapped QK^T.
// Q,K: [32 bh][2048][64] bf16 (Q pre-scaled by 0.125*log2e); Vt: [32 bh][64][2048] bf16
__global__ __launch_bounds__(256, 2) void k_attn(const u16* __restrict__ Qg, const u16* __restrict__ Kg,
                                                 const u16* __restrict__ Vtg, u16* __restrict__ Og) {
  __shared__ __align__(16) u16 sK[2][64 * 64];   // [key][d] swizzled, dbuf (8KB each)
  __shared__ __align__(16) u16 sV[2][64 * 64];   // [d][key] swizzled, dbuf
  __shared__ __align__(16) u16 sP[4][32 * 64];   // per-wave [q][key] swizzled (4KB each)
  const int t = threadIdx.x;
  const int lane = t & 63, g = lane >> 4, m16 = lane & 15, w = t >> 6;
  const int L = blockIdx.x;
  // bh = L&31 (4 heads per XCD -> K/V L2-resident); complementary q-tile pairing
  const int bh = L & 31;
  const int pair = (L >> 5) & 7;
  const int qt = (L < 256) ? pair : (15 - pair);
  const int b = bh >> 4, h = bh & 15;
  const u16* Qh = Qg + (long)bh * 2048 * 64;
  const u16* Kh = Kg + (long)bh * 2048 * 64;
  const u16* Vh = Vtg + (long)bh * 64 * 2048;

  char* sKb = (char*)sK;
  char* sVb = (char*)sV;
  char* sPw = (char*)sP + w * 4096;
  const f32x4 z = {0.f, 0.f, 0.f, 0.f};

  const int q0w = qt * 128 + w * 32;
  const int nkt = 2 * (qt + 1);

  auto stage = [&](int buf, int kbase) {
#pragma unroll
    for (int ps = 0; ps < 2; ++ps) {
      int i = ps * 256 + t;
      int r = i >> 3, c = i & 7, cs = c ^ (r & 7);
      async_lds16(sKb + buf * 8192 + i * 16, Kh + (long)(kbase + r) * 64 + cs * 8);
    }
#pragma unroll
    for (int ps = 0; ps < 2; ++ps) {
      int i = ps * 256 + t;
      int d = i >> 3, c = i & 7, cs = c ^ (d & 7);
      async_lds16(sVb + buf * 8192 + i * 16, Vh + (long)d * 2048 + kbase + cs * 8);
    }
  };

  // hoist Q fragments (B-operand: col=q via m16, k=d contiguous)
  bf16x8 qf[2][2];
#pragma unroll
  for (int mi = 0; mi < 2; ++mi)
#pragma unroll
    for (int k6 = 0; k6 < 2; ++k6)
      qf[mi][k6] = *(const bf16x8*)(Qh + (long)(q0w + mi * 16 + m16) * 64 + k6 * 32 + 8 * g);

  f32x4 acc[2][4];
#pragma unroll
  for (int mi = 0; mi < 2; ++mi)
#pragma unroll
    for (int n2 = 0; n2 < 4; ++n2) acc[mi][n2] = z;
  float m_run[2] = {-3.0e38f, -3.0e38f};
  float l_run[2] = {0.f, 0.f};

  int cur = 0;
  stage(0, 0);

  for (int kt = 0; kt < nkt; ++kt) {
    const int kbase = kt << 6;
    __syncthreads();  // drains previously-issued stage; tile `cur` ready
    if (kt + 1 < nkt) stage(cur ^ 1, kbase + 64);

    // wave-dead tile? (all keys above this wave's q range) -> skip compute
    if (kbase <= q0w + 31) {
      // ---- S^T = K * Q^T  (D: col=q=m16, row=key=n*16+4g+r)
      f32x4 s_[2][4];
#pragma unroll
      for (int mi = 0; mi < 2; ++mi)
#pragma unroll
        for (int n = 0; n < 4; ++n) s_[mi][n] = z;
      __builtin_amdgcn_s_setprio(1);
#pragma unroll
      for (int k6 = 0; k6 < 2; ++k6) {
#pragma unroll
        for (int n = 0; n < 4; ++n) {
          int row = n * 16 + m16;
          bf16x8 kf = *(const bf16x8*)(sKb + cur * 8192 + (row << 7) +
                                       ((k6 * 64 + 16 * g) ^ ((row & 7) << 4)));
          s_[0][n] = MFMA16(kf, qf[0][k6], s_[0][n]);
          s_[1][n] = MFMA16(kf, qf[1][k6], s_[1][n]);
        }
      }
      __builtin_amdgcn_s_setprio(0);

      const bool need_mask = (kbase + 63 > q0w);
#pragma unroll
      for (int mi = 0; mi < 2; ++mi) {
        const int qa = q0w + mi * 16 + m16;
        if (need_mask) {
#pragma unroll
          for (int n = 0; n < 4; ++n)
#pragma unroll
            for (int r = 0; r < 4; ++r)
              if (kbase + n * 16 + 4 * g + r > qa) s_[mi][n][r] = -3.0e38f;
        }
        float mx = s_[mi][0][0];
#pragma unroll
        for (int n = 0; n < 4; ++n)
#pragma unroll
          for (int r = 0; r < 4; ++r) mx = fmaxf(mx, s_[mi][n][r]);
        mx = fmaxf(mx, __shfl_xor(mx, 16));
        mx = fmaxf(mx, __shfl_xor(mx, 32));
        if (!__all(mx <= m_run[mi] + 8.0f)) {  // defer-max
          float mnew = fmaxf(m_run[mi], mx);
          float sc = exp2f(m_run[mi] - mnew);
          m_run[mi] = mnew;
          l_run[mi] *= sc;
#pragma unroll
          for (int r = 0; r < 4; ++r) {
            float scr = __shfl(sc, 4 * g + r);
#pragma unroll
            for (int n2 = 0; n2 < 4; ++n2) acc[mi][n2][r] *= scr;
          }
        }
        float rs = 0.f;
        const int qrow = mi * 16 + m16;
#pragma unroll
        for (int n = 0; n < 4; ++n) {
          float p0 = exp2f(s_[mi][n][0] - m_run[mi]);
          float p1 = exp2f(s_[mi][n][1] - m_run[mi]);
          float p2 = exp2f(s_[mi][n][2] - m_run[mi]);
          float p3 = exp2f(s_[mi][n][3] - m_run[mi]);
          rs += (p0 + p1) + (p2 + p3);
          u32 w0 = cvt_pk_bf16(p0, p1);
          u32 w1 = cvt_pk_bf16(p2, p3);
          int boff = (qrow << 7) + ((32 * n + 8 * g) ^ ((m16 & 7) << 4));
          *(uint2*)(sPw + boff) = make_uint2(w0, w1);
        }
        rs += __shfl_xor(rs, 16);
        rs += __shfl_xor(rs, 32);
        l_run[mi] += rs;
      }

      // ---- O += P V
      __builtin_amdgcn_s_setprio(1);
#pragma unroll
      for (int kk = 0; kk < 2; ++kk) {
        int koff = kk * 64 + 16 * g;
        bf16x8 pa0 = *(const bf16x8*)(sPw + (m16 << 7) + (koff ^ ((m16 & 7) << 4)));
        bf16x8 pa1 = *(const bf16x8*)(sPw + ((16 + m16) << 7) + (koff ^ ((m16 & 7) << 4)));
#pragma unroll
        for (int n2 = 0; n2 < 4; ++n2) {
          int vrow = n2 * 16 + m16;
          bf16x8 vf = *(const bf16x8*)(sVb + cur * 8192 + (vrow << 7) +
                                       (koff ^ ((vrow & 7) << 4)));
          acc[0][n2] = MFMA16(pa0, vf, acc[0][n2]);
          acc[1][n2] = MFMA16(pa1, vf, acc[1][n2]);
        }
      }
      __builtin_amdgcn_s_setprio(0);
    }
    cur ^= 1;
  }

  // epilogue
#pragma unroll
  for (int mi = 0; mi < 2; ++mi) {
#pragma unroll
    for (int r = 0; r < 4; ++r) {
      float lf = __shfl(l_run[mi], 4 * g + r);
      float inv = 1.0f / lf;
      int q = q0w + mi * 16 + 4 * g + r;
      long orow = (long)b * 2048 + q;
#pragma unroll
      for (int n2 = 0; n2 < 4; ++n2) {
        int col = h * 64 + n2 * 16 + m16;
        Og[orow * 1024 + col] = f2bf(acc[mi][n2][r] * inv);
      }
    }
  }
}

// ---------------- launch ----------------

extern "C" void kernel_launch(void* const* d_in, const int* in_sizes, int n_in,
                              void* d_out, int out_size, void* d_ws, size_t ws_size,
                              hipStream_t stream) {
  const float* x = (const float*)d_in[0];
  const float* w_qkv = (const float*)d_in[1];
  const float* w_out = (const float*)d_in[2];
  float* out = (float*)d_out;
  char* ws = (char*)d_ws;

  u16* xb    = (u16*)(ws + 0);          // 8 MB, reused as Ob after attention
  u16* wqkvT = (u16*)(ws + 8388608L);   // 6 MB
  u16* woutT = (u16*)(ws + 14680064L);  // 2 MB
  u16* Qb    = (u16*)(ws + 16777216L);  // 8 MB
  u16* Kb    = (u16*)(ws + 25165824L);  // 8 MB
  u16* Vb    = (u16*)(ws + 33554432L);  // 8 MB
  u16* Vt    = (u16*)(ws + 41943040L);  // 8 MB  (total 48 MB)
  u16* Ob    = xb;                      // alias: xb dead after GEMM1

  k_cvt<<<4096, 256, 0, stream>>>(x, xb, 4194304);
  k_transpose_cvt<<<dim3(96, 32), 256, 0, stream>>>(w_qkv, wqkvT, 1024, 3072);
  k_transpose_cvt<<<dim3(32, 32), 256, 0, stream>>>(w_out, woutT, 1024, 1024);
  k_gemm_qkv<<<dim3(24, 32), 256, 0, stream>>>(xb, wqkvT, Qb, Kb, Vb);
  k_transpose_v<<<dim3(64, 2, 32), 256, 0, stream>>>(Vb, Vt);
  k_attn<<<dim3(512), 256, 0, stream>>>(Qb, Kb, Vt, Ob);
  k_gemm_out<<<dim3(8, 32), 256, 0, stream>>>(Ob, woutT, out);
}